// Round 3
// baseline (258.096 us; speedup 1.0000x reference)
//
#include <hip/hip_runtime.h>

// y: [B=8, C=192, H=64, W=64] float32; codebooks: [G=8, K=512, d=24] float32
// d_out: float32, concatenated flat in return order:
//   universal_ctx [B,C,H,W] (6291456) | y_ba [B,C,H,W] (6291456) | code_index [B,1,G,H,W] (262144)
#define B_   8
#define C_   192
#define HW_  4096      // 64*64
#define G_   8
#define K_   512
#define D_   24
#define NPOS (B_ * HW_)               // 32768 spatial positions
#define THREADS 256
#define POS_PER_BLOCK (2 * THREADS)   // 512; each thread handles 2 positions

__global__ __launch_bounds__(THREADS) void vq_argmin_kernel(
    const float* __restrict__ y,
    const float* __restrict__ cb,
    float* __restrict__ out)
{
    __shared__ float  sE[K_ * D_];     // this block's group codebook, 48 KiB
    __shared__ double sE2[K_];         // fp64 ||e||^2

    const int bid   = blockIdx.x;
    const int g     = bid & (G_ - 1);
    const int chunk = bid >> 3;
    const int tid   = threadIdx.x;

    // ---- Stage codebook group g into LDS ----
    const float* cbg = cb + (size_t)g * (K_ * D_);
    for (int i = tid; i < K_ * D_; i += THREADS) {
        sE[i] = cbg[i];
    }
    __syncthreads();

    // ---- e2[k] in fp64 (f32 products exact in fp64) ----
    for (int k = tid; k < K_; k += THREADS) {
        double s = 0.0;
        #pragma unroll
        for (int j = 0; j < D_; ++j) {
            double v = (double)sE[k * D_ + j];
            s = fma(v, v, s);
        }
        sE2[k] = s;
    }
    __syncthreads();

    // ---- Two positions per thread ----
    const int p0 = chunk * POS_PER_BLOCK + tid;
    const int p1 = p0 + THREADS;
    const int b0 = p0 >> 12, hw0 = p0 & (HW_ - 1);
    const int b1 = p1 >> 12, hw1 = p1 & (HW_ - 1);
    const size_t base0 = ((size_t)b0 * C_ + g * D_) * HW_ + hw0;
    const size_t base1 = ((size_t)b1 * C_ + g * D_) * HW_ + hw1;

    double x0[D_], x1[D_];
    #pragma unroll
    for (int j = 0; j < D_; ++j) {
        x0[j] = (double)y[base0 + (size_t)j * HW_];   // coalesced across lanes per j
        x1[j] = (double)y[base1 + (size_t)j * HW_];
    }

    // ---- argmin over K of (e2 - 2*x.e); x2 constant per position -> same ordering.
    //      Strict '<' keeps first (lowest-k) min, matching np.argmin tie rule. ----
    double best0 = 1e300, best1 = 1e300;
    int    bi0 = 0, bi1 = 0;
    for (int k = 0; k < K_; ++k) {
        const float* e = &sE[k * D_];   // wave-uniform address -> LDS broadcast
        double s0 = 0.0, s1 = 0.0;
        #pragma unroll
        for (int j = 0; j < D_; ++j) {
            double ev = (double)e[j];
            s0 = fma(x0[j], ev, s0);
            s1 = fma(x1[j], ev, s1);
        }
        double d0 = fma(-2.0, s0, sE2[k]);
        double d1 = fma(-2.0, s1, sE2[k]);
        if (d0 < best0) { best0 = d0; bi0 = k; }
        if (d1 < best1) { best1 = d1; bi1 = k; }
    }

    // ---- Write f32 outputs: universal_ctx == y_ba == selected code ----
    float* out0 = out;                                   // universal_ctx
    float* out1 = out + (size_t)B_ * C_ * HW_;           // y_ba
    float* out2 = out + (size_t)2 * B_ * C_ * HW_;       // code_index [B,G,H,W]

    #pragma unroll
    for (int j = 0; j < D_; ++j) {
        float q0 = sE[bi0 * D_ + j];
        float q1 = sE[bi1 * D_ + j];
        out0[base0 + (size_t)j * HW_] = q0;
        out1[base0 + (size_t)j * HW_] = q0;
        out0[base1 + (size_t)j * HW_] = q1;
        out1[base1 + (size_t)j * HW_] = q1;
    }
    out2[((size_t)b0 * G_ + g) * HW_ + hw0] = (float)bi0;
    out2[((size_t)b1 * G_ + g) * HW_ + hw1] = (float)bi1;
}

extern "C" void kernel_launch(void* const* d_in, const int* in_sizes, int n_in,
                              void* d_out, int out_size, void* d_ws, size_t ws_size,
                              hipStream_t stream) {
    const float* y  = (const float*)d_in[0];
    const float* cb = (const float*)d_in[1];
    float* out = (float*)d_out;

    const int nblocks = (NPOS / POS_PER_BLOCK) * G_;   // 64 * 8 = 512
    vq_argmin_kernel<<<dim3(nblocks), dim3(THREADS), 0, stream>>>(y, cb, out);
}

// Round 4
// 176.662 us; speedup vs baseline: 1.4610x; 1.4610x over previous
//
#include <hip/hip_runtime.h>

// y: [B=8, C=192, H=64, W=64] float32; codebooks: [G=8, K=512, d=24] float32
// d_out: float32, concatenated flat in return order:
//   universal_ctx [B,C,H,W] (6291456) | y_ba [B,C,H,W] (6291456) | code_index [B,1,G,H,W] (262144)
#define B_   8
#define C_   192
#define HW_  4096      // 64*64
#define G_   8
#define K_   512
#define D_   24
#define ROWF 28        // padded row: e[0..23], e2f at [24], pad -> 112 B (16B aligned)
#define NPOS (B_ * HW_)               // 32768 spatial positions
#define THREADS 256
#define POS_PER_BLOCK (2 * THREADS)   // 512; each thread handles 2 positions

static __device__ __forceinline__ unsigned umin_(unsigned a, unsigned b) { return a < b ? a : b; }
static __device__ __forceinline__ unsigned umax_(unsigned a, unsigned b) { return a > b ? a : b; }

__global__ __launch_bounds__(THREADS) void vq_argmin_kernel(
    const float* __restrict__ y,
    const float* __restrict__ cb,
    float* __restrict__ out)
{
    // Per-group codebook rows: [K][ROWF] floats; row k = {e_0..e_23, f32(||e||^2 + 128), pad}
    __shared__ float sRow[K_ * ROWF];     // 57,344 B (grid=2 blocks/CU -> LDS not occupancy-limiting)

    const int bid   = blockIdx.x;
    const int g     = bid & (G_ - 1);
    const int chunk = bid >> 3;
    const int tid   = threadIdx.x;

    // ---- Stage codebook group g into LDS ----
    const float* cbg = cb + (size_t)g * (K_ * D_);
    for (int i = tid; i < K_ * D_; i += THREADS) {
        int k = i / D_;
        int j = i - k * D_;
        sRow[k * ROWF + j] = cbg[i];
    }
    __syncthreads();

    // ---- row[24] = f32( ||e||^2 + 128 ), computed in fp64 ----
    for (int k = tid; k < K_; k += THREADS) {
        double s = 128.0;
        #pragma unroll
        for (int j = 0; j < D_; ++j) {
            double v = (double)sRow[k * ROWF + j];
            s = fma(v, v, s);
        }
        sRow[k * ROWF + D_] = (float)s;
    }
    __syncthreads();

    // ---- Two positions per thread ----
    const int p0 = chunk * POS_PER_BLOCK + tid;
    const int p1 = p0 + THREADS;
    const int b0 = p0 >> 12, hw0 = p0 & (HW_ - 1);
    const int b1p = p1 >> 12, hw1 = p1 & (HW_ - 1);
    const size_t base0 = ((size_t)b0 * C_ + g * D_) * HW_ + hw0;
    const size_t base1 = ((size_t)b1p * C_ + g * D_) * HW_ + hw1;

    float xm0[D_], xm1[D_];          // -2*x, fp32
    #pragma unroll
    for (int j = 0; j < D_; ++j) {
        xm0[j] = -2.0f * y[base0 + (size_t)j * HW_];   // coalesced per j
        xm1[j] = -2.0f * y[base1 + (size_t)j * HW_];
    }

    // ---- fp32 screen: key = (bits(dist+128) & ~0x1FF) | k ; track top-3 min keys.
    //      uint order == float order (dist+128 > 0 guaranteed); low 9 bits give
    //      tie -> lowest k, matching np.argmin. ----
    unsigned A1 = 0xFFFFFFFFu, A2 = 0xFFFFFFFFu, A3 = 0xFFFFFFFFu;  // pos0
    unsigned B1 = 0xFFFFFFFFu, B2 = 0xFFFFFFFFu, B3 = 0xFFFFFFFFu;  // pos1
    for (int k = 0; k < K_; ++k) {
        const float* row = &sRow[k * ROWF];      // wave-uniform -> LDS broadcast b128 reads
        float acc0 = row[D_];
        float acc1 = row[D_];
        #pragma unroll
        for (int j = 0; j < D_; ++j) {
            float e = row[j];
            acc0 = fmaf(xm0[j], e, acc0);
            acc1 = fmaf(xm1[j], e, acc1);
        }
        unsigned key0 = (__float_as_uint(acc0) & 0xFFFFFE00u) | (unsigned)k;
        unsigned key1 = (__float_as_uint(acc1) & 0xFFFFFE00u) | (unsigned)k;
        unsigned nA3 = umin_(umax_(A2, key0), A3);
        unsigned nA2 = umin_(umax_(A1, key0), A2);
        unsigned nA1 = umin_(A1, key0);
        A1 = nA1; A2 = nA2; A3 = nA3;
        unsigned nB3 = umin_(umax_(B2, key1), B3);
        unsigned nB2 = umin_(umax_(B1, key1), B2);
        unsigned nB1 = umin_(B1, key1);
        B1 = nB1; B2 = nB2; B3 = nB3;
    }

    // ---- Exact fp64 recheck of the 3 candidates per position ----
    double xd0[D_], xd1[D_];
    #pragma unroll
    for (int j = 0; j < D_; ++j) {
        xd0[j] = (double)xm0[j];    // exact: -2x in fp64
        xd1[j] = (double)xm1[j];
    }

    unsigned candA[3] = {A1, A2, A3};
    unsigned candB[3] = {B1, B2, B3};
    double bd0 = 1e300, bd1 = 1e300;
    int bi0 = K_, bi1 = K_;
    #pragma unroll
    for (int c = 0; c < 3; ++c) {
        {
            int k = (int)(candA[c] & 511u);
            const float* row = &sRow[k * ROWF];
            double s = 0.0;
            #pragma unroll
            for (int j = 0; j < D_; ++j) {
                double ev = (double)row[j];
                s = fma(ev, ev, s);          // e^2
                s = fma(xd0[j], ev, s);      // -2 x.e
            }
            if (s < bd0 || (s == bd0 && k < bi0)) { bd0 = s; bi0 = k; }
        }
        {
            int k = (int)(candB[c] & 511u);
            const float* row = &sRow[k * ROWF];
            double s = 0.0;
            #pragma unroll
            for (int j = 0; j < D_; ++j) {
                double ev = (double)row[j];
                s = fma(ev, ev, s);
                s = fma(xd1[j], ev, s);
            }
            if (s < bd1 || (s == bd1 && k < bi1)) { bd1 = s; bi1 = k; }
        }
    }

    // ---- Write f32 outputs: universal_ctx == y_ba == selected code ----
    float* out0 = out;                                   // universal_ctx
    float* out1 = out + (size_t)B_ * C_ * HW_;           // y_ba
    float* out2 = out + (size_t)2 * B_ * C_ * HW_;       // code_index [B,G,H,W]

    #pragma unroll
    for (int j = 0; j < D_; ++j) {
        float q0 = sRow[bi0 * ROWF + j];
        float q1 = sRow[bi1 * ROWF + j];
        out0[base0 + (size_t)j * HW_] = q0;
        out1[base0 + (size_t)j * HW_] = q0;
        out0[base1 + (size_t)j * HW_] = q1;
        out1[base1 + (size_t)j * HW_] = q1;
    }
    out2[((size_t)b0 * G_ + g) * HW_ + hw0] = (float)bi0;
    out2[((size_t)b1p * G_ + g) * HW_ + hw1] = (float)bi1;
}

extern "C" void kernel_launch(void* const* d_in, const int* in_sizes, int n_in,
                              void* d_out, int out_size, void* d_ws, size_t ws_size,
                              hipStream_t stream) {
    const float* y  = (const float*)d_in[0];
    const float* cb = (const float*)d_in[1];
    float* out = (float*)d_out;

    const int nblocks = (NPOS / POS_PER_BLOCK) * G_;   // 64 * 8 = 512 -> 2 blocks/CU
    vq_argmin_kernel<<<dim3(nblocks), dim3(THREADS), 0, stream>>>(y, cb, out);
}

// Round 6
// 162.266 us; speedup vs baseline: 1.5906x; 1.0887x over previous
//
#include <hip/hip_runtime.h>

// y: [B=8, C=192, H=64, W=64] f32; codebooks: [G=8, K=512, d=24] f32
// out (f32, concat): universal_ctx [B,C,H,W] | y_ba [B,C,H,W] | code_index [B,1,G,H,W]
#define B_   8
#define C_   192
#define HW_  4096
#define G_   8
#define K_   512
#define D_   24
#define CBSZ (K_ * D_)       // 12288 floats per group
#define THREADS 256          // 4 waves; block = (chunk of 512 positions) x (group g)

typedef float  f32x4 __attribute__((ext_vector_type(4)));
typedef short  s16x8 __attribute__((ext_vector_type(8)));
typedef unsigned long long u64;

static __device__ __forceinline__ unsigned umin_(unsigned a, unsigned b) { return a < b ? a : b; }
static __device__ __forceinline__ unsigned umax_(unsigned a, unsigned b) { return a > b ? a : b; }
static __device__ __forceinline__ u64 qmin_(u64 a, u64 b) { return a < b ? a : b; }
static __device__ __forceinline__ u64 qmax_(u64 a, u64 b) { return a > b ? a : b; }
// round-to-nearest-even f32 -> bf16 bits
static __device__ __forceinline__ unsigned short f2bf(float x) {
    unsigned u = __float_as_uint(x);
    return (unsigned short)((u + 0x7FFFu + ((u >> 16) & 1u)) >> 16);
}
static __device__ __forceinline__ float bf2f(unsigned short h) {
    return __uint_as_float(((unsigned)h) << 16);
}

__global__ __launch_bounds__(THREADS) void vq_mfma_kernel(
    const float* __restrict__ y,
    const float* __restrict__ cb,
    float* __restrict__ out)
{
    // B-fragments: [tile t:32][split s:2][lane:64][j:8] bf16 halfwords (64 KiB)
    __shared__ unsigned short sB[32 * 2 * 64 * 8];
    __shared__ float sE2f[K_];            // f32(||e||^2 + 256)

    const int bid   = blockIdx.x;
    const int g     = bid & (G_ - 1);
    const int chunk = bid >> 3;
    const int tid   = threadIdx.x;
    const int wave  = tid >> 6;
    const int lane  = tid & 63;
    const int c     = lane & 15;          // N-col (codes) for B/C/D; M-row (position) for A
    const int q     = lane >> 4;          // quad

    const float* cbg = cb + (size_t)g * CBSZ;

    // ---- zero the K=24..31 pad region of sB (dword view) ----
    {
        unsigned* sBw = (unsigned*)sB;
        for (int i = tid; i < 64 * 64; i += THREADS) {
            int ts = i >> 6, w = i & 63;
            sBw[ts * 256 + 192 + w] = 0u;
        }
    }
    // ---- stage codebook as bf16 hi/lo fragments ----
    for (int i = tid; i < CBSZ; i += THREADS) {
        int n = i / D_;           // code
        int k = i - n * D_;       // dim
        float e = cbg[i];         // coalesced
        unsigned short hb = f2bf(e);
        unsigned short lb = f2bf(e - bf2f(hb));
        int t = n >> 4, cc = n & 15, qq = k >> 3, j = k & 7;
        int l = qq * 16 + cc;
        sB[(t * 2 + 0) * 512 + l * 8 + j] = hb;
        sB[(t * 2 + 1) * 512 + l * 8 + j] = lb;
    }
    // ---- e2 + 256 in fp64, rounded to f32 ----
    for (int n = tid; n < K_; n += THREADS) {
        double s = 256.0;
        #pragma unroll
        for (int j = 0; j < D_; ++j) {
            double v = (double)cbg[n * D_ + j];
            s = fma(v, v, s);
        }
        sE2f[n] = (float)s;
    }
    __syncthreads();

    float* out0 = out;
    float* out1 = out + (size_t)B_ * C_ * HW_;
    float* out2 = out + (size_t)2 * B_ * C_ * HW_;

    const int posbase = chunk * 512;

    for (int myTile = wave; myTile < 32; myTile += 4) {
        const int posT = posbase + myTile * 16;            // 16 consecutive positions
        const int bimg = posT >> 12;
        const int hw   = posT & (HW_ - 1);
        const size_t ybase = ((size_t)bimg * C_ + g * D_) * HW_ + hw;

        // ---- A fragment: lane holds (-2*x)[pos = posT + c][k = q*8+j]; q==3 -> 0 ----
        // THE R5 BUG WAS HERE: raw x gave screen e^2 + x.e (uncorrelated with the
        // true objective e^2 - 2x.e). Scale by -2 so MFMA accumulates -2 x.e.
        s16x8 Ah, Al;
        {
            float xf[8];
            if (q < 3) {
                #pragma unroll
                for (int j = 0; j < 8; ++j)
                    xf[j] = -2.0f * y[ybase + (size_t)(q * 8 + j) * HW_ + c];
            } else {
                #pragma unroll
                for (int j = 0; j < 8; ++j) xf[j] = 0.0f;
            }
            #pragma unroll
            for (int j = 0; j < 8; ++j) {
                unsigned short hb = f2bf(xf[j]);
                unsigned short lb = f2bf(xf[j] - bf2f(hb));
                Ah[j] = (short)hb;
                Al[j] = (short)lb;
            }
        }

        // ---- screen 32 code-tiles: 3 MFMA passes, per-lane top-2 (5-bit tile keys) ----
        unsigned b1[4], b2[4];
        #pragma unroll
        for (int r = 0; r < 4; ++r) { b1[r] = 0xFFFFFFFFu; b2[r] = 0xFFFFFFFFu; }

        #pragma unroll 4
        for (int t = 0; t < 32; ++t) {
            const s16x8 bh = *(const s16x8*)(sB + t * 1024 + lane * 8);
            const s16x8 bl = *(const s16x8*)(sB + t * 1024 + 512 + lane * 8);
            float e2v = sE2f[(t << 4) + c];
            f32x4 acc = { e2v, e2v, e2v, e2v };
            acc = __builtin_amdgcn_mfma_f32_16x16x32_bf16(Ah, bh, acc, 0, 0, 0);
            acc = __builtin_amdgcn_mfma_f32_16x16x32_bf16(Ah, bl, acc, 0, 0, 0);
            acc = __builtin_amdgcn_mfma_f32_16x16x32_bf16(Al, bh, acc, 0, 0, 0);
            #pragma unroll
            for (int r = 0; r < 4; ++r) {
                unsigned key = (__float_as_uint(acc[r]) & 0xFFFFFFE0u) | (unsigned)t;
                b2[r] = umin_(umax_(b1[r], key), b2[r]);
                b1[r] = umin_(b1[r], key);
            }
        }

        // ---- rebuild 64-bit keys (27 value bits << 9 | 9-bit code): no extra
        //      quantization; butterfly-merge per-row top-3 across 16 columns ----
        u64 u1[4], u2[4], u3[4];
        #pragma unroll
        for (int r = 0; r < 4; ++r) {
            u1[r] = ((u64)(b1[r] & 0xFFFFFFE0u) << 9) | (u64)(((b1[r] & 31u) << 4) | (unsigned)c);
            u2[r] = ((u64)(b2[r] & 0xFFFFFFE0u) << 9) | (u64)(((b2[r] & 31u) << 4) | (unsigned)c);
            u3[r] = ~0ull;
        }
        #pragma unroll
        for (int d = 1; d < 16; d <<= 1) {
            #pragma unroll
            for (int r = 0; r < 4; ++r) {
                u64 o1 = __shfl_xor(u1[r], d);
                u64 o2 = __shfl_xor(u2[r], d);
                u64 o3 = __shfl_xor(u3[r], d);
                u64 x  = qmax_(u1[r], o1);
                u64 yv = qmin_(u2[r], o2);
                u64 w  = qmax_(u2[r], o2);
                u64 z  = qmin_(u3[r], o3);
                u1[r] = qmin_(u1[r], o1);
                u2[r] = qmin_(x, yv);
                u3[r] = qmin_(qmax_(x, yv), qmin_(w, z));
            }
        }

        // ---- fp64 recheck: lane c = 4*rr + cand; row = 4*q + rr ----
        const int rr   = c >> 2;
        const int cand = c & 3;
        const int row  = (q << 2) + rr;
        u64 selA = (rr == 0) ? u1[0] : (rr == 1) ? u1[1] : (rr == 2) ? u1[2] : u1[3];
        u64 selB = (rr == 0) ? u2[0] : (rr == 1) ? u2[1] : (rr == 2) ? u2[2] : u2[3];
        u64 selC = (rr == 0) ? u3[0] : (rr == 1) ? u3[1] : (rr == 2) ? u3[2] : u3[3];
        u64 sel  = (cand == 0) ? selA : (cand == 1) ? selB : selC;
        int kc   = (int)(sel & 511ull);

        const float* ce = cbg + kc * D_;
        double s = 256.0;
        #pragma unroll
        for (int j = 0; j < D_; ++j) {
            double ev = (double)ce[j];
            double xm = -2.0 * (double)y[ybase + (size_t)j * HW_ + row];
            s = fma(ev, ev, s);
            s = fma(xm, ev, s);
        }
        u64 key64 = (((u64)__double_as_longlong(s)) & ~0x1FFull) | (u64)kc;
        if (cand == 3) key64 = ~0ull;

        u64 o = __shfl_xor(key64, 1);
        key64 = o < key64 ? o : key64;
        o = __shfl_xor(key64, 2);
        key64 = o < key64 ? o : key64;
        int kwin = (int)(key64 & 511ull);

        // ---- writer lanes (cand==0): 16 lanes cover the 16 rows ----
        if (cand == 0) {
            const float* cw = cbg + kwin * D_;
            #pragma unroll
            for (int j = 0; j < D_; ++j) {
                float qv = cw[j];
                size_t oo = ybase + (size_t)j * HW_ + row;
                out0[oo] = qv;
                out1[oo] = qv;
            }
            out2[((size_t)bimg * G_ + g) * HW_ + hw + row] = (float)kwin;
        }
    }
}

extern "C" void kernel_launch(void* const* d_in, const int* in_sizes, int n_in,
                              void* d_out, int out_size, void* d_ws, size_t ws_size,
                              hipStream_t stream) {
    const float* y  = (const float*)d_in[0];
    const float* cb = (const float*)d_in[1];
    float* out = (float*)d_out;

    const int nblocks = 64 * G_;   // 64 chunks of 512 positions x 8 groups = 512
    vq_mfma_kernel<<<dim3(nblocks), dim3(THREADS), 0, stream>>>(y, cb, out);
}

// Round 7
// 121.240 us; speedup vs baseline: 2.1288x; 1.3384x over previous
//
#include <hip/hip_runtime.h>

// y: [B=8, C=192, H=64, W=64] f32; codebooks: [G=8, K=512, d=24] f32
// out (f32, concat): universal_ctx | y_ba | code_index [B,1,G,H,W]
#define B_   8
#define C_   192
#define HW_  4096
#define G_   8
#define K_   512
#define D_   24
#define CBSZ (K_ * D_)
#define THREADS 256
#define TILES_PER_BLOCK 16    // 256 positions per block / 16

typedef float  f32x4 __attribute__((ext_vector_type(4)));
typedef short  s16x8 __attribute__((ext_vector_type(8)));
typedef short  s16x4 __attribute__((ext_vector_type(4)));
typedef unsigned long long u64;

static __device__ __forceinline__ unsigned umin_(unsigned a, unsigned b){return a<b?a:b;}
static __device__ __forceinline__ unsigned umax_(unsigned a, unsigned b){return a>b?a:b;}
static __device__ __forceinline__ unsigned short f2bf(float x){       // RNE f32->bf16
    unsigned u=__float_as_uint(x);
    return (unsigned short)((u + 0x7FFFu + ((u>>16)&1u))>>16);
}
static __device__ __forceinline__ float bf2f(unsigned short h){return __uint_as_float(((unsigned)h)<<16);}

__global__ __launch_bounds__(THREADS, 4) void vq_mfma2(
    const float* __restrict__ y, const float* __restrict__ cb, float* __restrict__ out)
{
    // [tile:32][lane:64][j:8] bf16 halfwords; lanes 0..47 = e_hi fragments (k<24),
    // lanes 48..63 j=0,1 = e2_hi/e2_lo (k=24,25; A=1.0 there), j>=2 zero. 32 KiB.
    __shared__ unsigned short sB[32 * 512];

    const int bid = blockIdx.x;
    const int g = bid & 7;
    const int chunk = bid >> 3;
    const int tid = threadIdx.x;
    const int wave = tid >> 6, lane = tid & 63;
    const int c = lane & 15, q = lane >> 4;

    const float* cbg = cb + (size_t)g * CBSZ;

    // ---- stage codebook hi-bf16 fragments (float4 loads, b64 LDS writes) ----
    {
        const f32x4* cb4 = (const f32x4*)cbg;
        for (int i = tid; i < CBSZ/4; i += THREADS) {
            f32x4 v = cb4[i];
            int i4 = i << 2;
            int n  = i4 / 24;          // code; float4 never crosses a row (24%4==0)
            int k0 = i4 - n * 24;
            int off = (n >> 4) * 512 + (((k0 >> 3) << 4) + (n & 15)) * 8 + (k0 & 7);
            s16x4 h;
            h[0]=(short)f2bf(v[0]); h[1]=(short)f2bf(v[1]);
            h[2]=(short)f2bf(v[2]); h[3]=(short)f2bf(v[3]);
            *(s16x4*)(&sB[off]) = h;
        }
        // e2 as bf16 pair in k=24,25; zero k=26..31
        for (int n = tid; n < K_; n += THREADS) {
            const float* row = cbg + n * D_;
            double s = 0.0;
            #pragma unroll
            for (int j = 0; j < D_; ++j) { double v = (double)row[j]; s = fma(v,v,s); }
            unsigned short ehi = f2bf((float)s);
            unsigned short elo = f2bf((float)(s - (double)bf2f(ehi)));
            unsigned* dst = (unsigned*)(&sB[(n >> 4) * 512 + (48 + (n & 15)) * 8]);
            dst[0] = (unsigned)ehi | ((unsigned)elo << 16);
            dst[1] = 0u; dst[2] = 0u; dst[3] = 0u;
        }
    }
    __syncthreads();

    float* out0 = out;
    float* out1 = out + (size_t)(B_*C_)*HW_;
    float* out2 = out + (size_t)(2*B_*C_)*HW_;

    for (int mt = wave; mt < TILES_PER_BLOCK; mt += 4) {
        const int posT = chunk * 256 + mt * 16;
        const int bimg = posT >> 12;
        const int hw   = posT & (HW_-1);
        const size_t ybase = ((size_t)bimg*C_ + g*D_)*HW_ + hw;

        // A: lane (c,q) holds (-2x)[pos=posT+c][k=q*8+j]; q==3: k=24,25 -> 1.0 (lo=0)
        s16x8 Ah = {0,0,0,0,0,0,0,0}, Al = {0,0,0,0,0,0,0,0};
        if (q < 3) {
            #pragma unroll
            for (int j = 0; j < 8; ++j) {
                float xv = -2.0f * y[ybase + (size_t)(q*8+j)*HW_ + c];
                unsigned short hb = f2bf(xv);
                Ah[j] = (short)hb;
                Al[j] = (short)f2bf(xv - bf2f(hb));
            }
        } else {
            Ah[0] = (short)0x3F80; Ah[1] = (short)0x3F80;   // 1.0bf16 for e2 dims
        }

        // ---- screen: 32 tiles x 2 MFMA; per-lane top-2 (5-bit tile keys, quant 2^-10) ----
        unsigned b1[4], b2[4];
        #pragma unroll
        for (int r=0;r<4;++r){ b1[r]=0xFFFFFFFFu; b2[r]=0xFFFFFFFFu; }

        #pragma unroll 8
        for (int t = 0; t < 32; ++t) {
            s16x8 bh = *(const s16x8*)(&sB[t*512 + lane*8]);
            f32x4 acc = {256.0f, 256.0f, 256.0f, 256.0f};
            acc = __builtin_amdgcn_mfma_f32_16x16x32_bf16(Ah, bh, acc, 0,0,0);
            acc = __builtin_amdgcn_mfma_f32_16x16x32_bf16(Al, bh, acc, 0,0,0);
            #pragma unroll
            for (int r=0;r<4;++r){
                unsigned key = (__float_as_uint(acc[r]) & 0xFFFFFFE0u) | (unsigned)t;
                b2[r] = umin_(umax_(b1[r], key), b2[r]);
                b1[r] = umin_(b1[r], key);
            }
        }

        // ---- rebuild 9-bit-code keys (quant 2^-6); butterfly top-3 across 16 cols ----
        unsigned u1[4],u2[4],u3[4];
        #pragma unroll
        for (int r=0;r<4;++r){
            u1[r] = (b1[r] & 0xFFFFFE00u) | (((b1[r]&31u)<<4) | (unsigned)c);
            u2[r] = (b2[r] & 0xFFFFFE00u) | (((b2[r]&31u)<<4) | (unsigned)c);
            u3[r] = 0xFFFFFFFFu;
        }
        #pragma unroll
        for (int d=1; d<16; d<<=1){
            #pragma unroll
            for (int r=0;r<4;++r){
                unsigned o1=__shfl_xor(u1[r],d,64), o2=__shfl_xor(u2[r],d,64), o3=__shfl_xor(u3[r],d,64);
                unsigned x = umax_(u1[r],o1);
                unsigned yv= umin_(u2[r],o2);
                unsigned w = umax_(u2[r],o2);
                unsigned z = umin_(u3[r],o3);
                u1[r]=umin_(u1[r],o1);
                u2[r]=umin_(x,yv);
                u3[r]=umin_(umax_(x,yv), umin_(w,z));
            }
        }

        // ---- fp64 recheck: lane (row=(q<<2)+(c>>2), cand=c&3) ----
        const int rr = c >> 2, cand = c & 3, row = (q<<2) + rr;
        unsigned s1v = (rr==0)?u1[0]:(rr==1)?u1[1]:(rr==2)?u1[2]:u1[3];
        unsigned s2v = (rr==0)?u2[0]:(rr==1)?u2[1]:(rr==2)?u2[2]:u2[3];
        unsigned s3v = (rr==0)?u3[0]:(rr==1)?u3[1]:(rr==2)?u3[2]:u3[3];
        unsigned sel = (cand==0)?s1v:(cand==1)?s2v:s3v;
        int kc = (int)(sel & 511u);

        const f32x4* ce4 = (const f32x4*)(cbg + kc * D_);
        float ef[24];
        #pragma unroll
        for (int v=0; v<6; ++v) *(f32x4*)&ef[v*4] = ce4[v];
        double s = 256.0;
        #pragma unroll
        for (int j=0;j<24;++j){
            double ev = (double)ef[j];
            double xv = -2.0 * (double)y[ybase + (size_t)j*HW_ + row];
            s = fma(ev, ev, s);
            s = fma(xv, ev, s);
        }
        u64 key64 = (((u64)__double_as_longlong(s)) & ~0x1FFull) | (u64)kc;
        if (cand == 3) key64 = ~0ull;
        u64 o = __shfl_xor(key64, 1, 64); key64 = o < key64 ? o : key64;
        o = __shfl_xor(key64, 2, 64);     key64 = o < key64 ? o : key64;
        int kwin = (int)(key64 & 511ull);   // every lane in quad has row's winner

    // ---- cooperative epilogue: all 64 lanes write 24ch x 16pos x 2 outputs ----
        const int p = c;                                  // pos-in-tile this lane writes
        const int srcl = ((p>>2)<<4) | ((p&3)<<2);        // lane holding kwin[row=p]
        int kw = __shfl(kwin, srcl, 64);
        const float* cw = cbg + kw * D_;
        #pragma unroll
        for (int i=0;i<6;++i){
            int ch = i*4 + q;
            float val = cw[ch];                            // L1-hot gather, exact f32
            size_t oo = ybase + (size_t)ch*HW_ + p;
            out0[oo] = val;
            out1[oo] = val;
        }
        if (lane < 16)
            out2[((size_t)bimg*G_ + g)*HW_ + hw + lane] = (float)kw;
    }
}

extern "C" void kernel_launch(void* const* d_in, const int* in_sizes, int n_in,
                              void* d_out, int out_size, void* d_ws, size_t ws_size,
                              hipStream_t stream) {
    const float* y  = (const float*)d_in[0];
    const float* cb = (const float*)d_in[1];
    float* out = (float*)d_out;

    const int nblocks = 128 * G_;   // 128 chunks of 256 positions x 8 groups = 1024
    vq_mfma2<<<dim3(nblocks), dim3(THREADS), 0, stream>>>(y, cb, out);
}